// Round 1
// baseline (79.661 us; speedup 1.0000x reference)
//
#include <hip/hip_runtime.h>

#define BN 512   // batch
#define DD 512   // feature dim
#define LL 24    // label dim

// ---------------- prep: row norms + label bitmasks + zero accumulators -------
__global__ void prep_kernel(const float* __restrict__ src, const int* __restrict__ labels,
                            float* __restrict__ norms, unsigned* __restrict__ masks,
                            float* __restrict__ accum) {
    int i = blockIdx.x;        // one row per block, block = 64 (one wave)
    int lane = threadIdx.x;
    const float4* row = (const float4*)(src + (size_t)i * DD);
    float4 v0 = row[lane];
    float4 v1 = row[lane + 64];
    float s = v0.x*v0.x + v0.y*v0.y + v0.z*v0.z + v0.w*v0.w
            + v1.x*v1.x + v1.y*v1.y + v1.z*v1.z + v1.w*v1.w;
#pragma unroll
    for (int off = 32; off > 0; off >>= 1) s += __shfl_down(s, off);
    int lab = (lane < LL) ? labels[i * LL + lane] : 0;
    unsigned long long b = __ballot(lab != 0);
    if (lane == 0) {
        norms[i] = s;
        masks[i] = (unsigned)(b & 0xFFFFFFull);
        if (i == 0) { accum[0] = 0.0f; ((unsigned*)accum)[1] = 0u; }
    }
}

// ---------------- dist: D[i][j] = ||s_i - s_j||  via Gram matrix -------------
__device__ __forceinline__ float dist_val(float d2, bool diag) {
    d2 = fmaxf(d2, 0.0f);
    float d = sqrtf(d2);
    return diag ? 0.0f : d;
}

__global__ void dist_kernel(const float* __restrict__ S, const float* __restrict__ norms,
                            float* __restrict__ Dm) {
    // 32x32 output tile per block, 256 threads (16x16), 2x2 micro-tile.
    // LDS tiles stored transposed: As[k][row] so micro reads are float2.
    __shared__ float As[32][34];
    __shared__ float Bs[32][34];
    int t  = threadIdx.x;
    int tx = t & 15, ty = t >> 4;
    int jb = blockIdx.x * 32;
    int ib = blockIdx.y * 32;
    int lr = t >> 3;            // 0..31  (tile row)
    int lc = (t & 7) * 4;       // 0,4,...,28 (k offset)
    float acc00 = 0.f, acc01 = 0.f, acc10 = 0.f, acc11 = 0.f;
    for (int k0 = 0; k0 < DD; k0 += 32) {
        float4 a = *(const float4*)&S[(size_t)(ib + lr) * DD + k0 + lc];
        float4 b = *(const float4*)&S[(size_t)(jb + lr) * DD + k0 + lc];
        As[lc + 0][lr] = a.x; As[lc + 1][lr] = a.y; As[lc + 2][lr] = a.z; As[lc + 3][lr] = a.w;
        Bs[lc + 0][lr] = b.x; Bs[lc + 1][lr] = b.y; Bs[lc + 2][lr] = b.z; Bs[lc + 3][lr] = b.w;
        __syncthreads();
#pragma unroll
        for (int kk = 0; kk < 32; kk++) {
            float2 av = *(const float2*)&As[kk][ty * 2];
            float2 bv = *(const float2*)&Bs[kk][tx * 2];
            acc00 += av.x * bv.x; acc01 += av.x * bv.y;
            acc10 += av.y * bv.x; acc11 += av.y * bv.y;
        }
        __syncthreads();
    }
    int i0 = ib + ty * 2, j0 = jb + tx * 2;
    float ni0 = norms[i0], ni1 = norms[i0 + 1];
    float nj0 = norms[j0], nj1 = norms[j0 + 1];
    Dm[(size_t)i0 * BN + j0]           = dist_val(ni0 + nj0 - 2.f * acc00, i0 == j0);
    Dm[(size_t)i0 * BN + j0 + 1]       = dist_val(ni0 + nj1 - 2.f * acc01, i0 == j0 + 1);
    Dm[(size_t)(i0 + 1) * BN + j0]     = dist_val(ni1 + nj0 - 2.f * acc10, i0 + 1 == j0);
    Dm[(size_t)(i0 + 1) * BN + j0 + 1] = dist_val(ni1 + nj1 - 2.f * acc11, i0 + 1 == j0 + 1);
}

// ---------------- triplet: per-anchor pos/neg compaction + pair sum ----------
__global__ void triplet_kernel(const float* __restrict__ Dm, const unsigned* __restrict__ masks,
                               float* __restrict__ accum) {
    __shared__ float drow[BN];
    __shared__ float pos[BN];
    __shared__ float neg[BN];
    __shared__ int pcnt, ncnt;
    __shared__ float wsum[4];
    __shared__ unsigned wcnt[4];
    int i = blockIdx.x;
    int t = threadIdx.x;   // 256
    if (t == 0) { pcnt = 0; ncnt = 0; }
    float2 dv = ((const float2*)(Dm + (size_t)i * BN))[t];
    drow[2 * t] = dv.x; drow[2 * t + 1] = dv.y;
    __syncthreads();
    unsigned mi = masks[i];
#pragma unroll
    for (int j = t; j < BN; j += 256) {
        float dj = drow[j];
        if (mi & masks[j]) { int p = atomicAdd(&pcnt, 1); pos[p] = dj; }
        else               { int p = atomicAdd(&ncnt, 1); neg[p] = dj; }
    }
    __syncthreads();
    int P = pcnt, N = ncnt;
    float sum = 0.f;
    unsigned cnt = 0;
    for (int p = t; p < P; p += 256) {
        float a = pos[p];
        for (int n = 0; n < N; n++) {
            float v = a - neg[n];
            sum += fmaxf(v, 0.0f);
            cnt += (v > 1e-16f) ? 1u : 0u;
        }
    }
#pragma unroll
    for (int off = 32; off > 0; off >>= 1) {
        sum += __shfl_down(sum, off);
        cnt += __shfl_down(cnt, off);
    }
    if ((t & 63) == 0) { wsum[t >> 6] = sum; wcnt[t >> 6] = cnt; }
    __syncthreads();
    if (t == 0) {
        sum = wsum[0] + wsum[1] + wsum[2] + wsum[3];
        cnt = wcnt[0] + wcnt[1] + wcnt[2] + wcnt[3];
        if (sum != 0.f || cnt != 0u) {
            atomicAdd(&accum[0], sum);
            atomicAdd((unsigned*)&accum[1], cnt);
        }
    }
}

// ---------------- finalize ---------------------------------------------------
__global__ void finalize_kernel(const float* __restrict__ accum, float* __restrict__ out) {
    if (threadIdx.x == 0) {
        float s = accum[0];
        float c = (float)((const unsigned*)accum)[1];
        out[0] = s / (c + 1e-16f);
    }
}

extern "C" void kernel_launch(void* const* d_in, const int* in_sizes, int n_in,
                              void* d_out, int out_size, void* d_ws, size_t ws_size,
                              hipStream_t stream) {
    const float* src    = (const float*)d_in[0];
    const int*   labels = (const int*)d_in[1];
    float* ws = (float*)d_ws;
    // ws layout (floats): [0,512) norms | [512,1024) masks | [1024, 1024+512*512) dist | accum(2)
    float*    norms = ws;
    unsigned* masks = (unsigned*)(ws + BN);
    float*    Dm    = ws + 2 * BN;
    float*    accum = ws + 2 * BN + (size_t)BN * BN;

    hipLaunchKernelGGL(prep_kernel,     dim3(BN),     dim3(64),  0, stream, src, labels, norms, masks, accum);
    hipLaunchKernelGGL(dist_kernel,     dim3(16, 16), dim3(256), 0, stream, src, norms, Dm);
    hipLaunchKernelGGL(triplet_kernel,  dim3(BN),     dim3(256), 0, stream, Dm, masks, accum);
    hipLaunchKernelGGL(finalize_kernel, dim3(1),      dim3(64),  0, stream, accum, (float*)d_out);
}